// Round 1
// baseline (1618.518 us; speedup 1.0000x reference)
//
#include <hip/hip_runtime.h>
#include <hip/hip_bf16.h>
#include <math.h>

// Problem constants
constexpr int Bq      = 2;
constexpr int Lq      = 2048;
constexpr int Dq      = 1024;
constexpr int DI      = 2048;   // D_INNER
constexpr int DTR     = 64;     // DT_RANK
constexpr int NST     = 16;     // D_STATE
constexpr int DCONV   = 4;
constexpr int M_ROWS  = Bq * Lq;        // 4096
constexpr int XZ_LD   = 2 * DI;         // 4096
constexpr int XDBL_LD = DTR + 2 * NST;  // 96

// scan chunking
constexpr int NC = 16;              // chunks along L
constexpr int CL = Lq / NC;         // 128 steps per chunk

// ---------------- workspace layout (floats) ----------------
constexpr size_t OFF_XZ   = 0;                             // (M_ROWS, 4096)
constexpr size_t SZ_XZ    = (size_t)M_ROWS * XZ_LD;        // 16.78M
constexpr size_t OFF_XDBL = OFF_XZ + SZ_XZ;                // (M_ROWS, 96)
constexpr size_t SZ_XDBL  = (size_t)M_ROWS * XDBL_LD;
constexpr size_t OFF_DT   = OFF_XDBL + SZ_XDBL;            // (M_ROWS, DI)
constexpr size_t SZ_DT    = (size_t)M_ROWS * DI;
constexpr size_t OFF_P    = OFF_DT + SZ_DT;                // (B,NC,NST,DI)
constexpr size_t SZ_PSH   = (size_t)Bq * NC * NST * DI;
constexpr size_t OFF_S    = OFF_P + SZ_PSH;
constexpr size_t OFF_H    = OFF_S + SZ_PSH;

__device__ __forceinline__ float silu_f(float x) {
    return x / (1.f + __expf(-x));
}

// ---------------------------------------------------------------------------
// Generic f32 NT GEMM:  C[m,n] = sum_k A[m*lda+k] * Bm[n*ldb+k]
// 128x128 tile, BK=16, 256 threads, 8x8 microtile.
// EPI==0: plain store.  EPI==1: bias + softplus.
// ---------------------------------------------------------------------------
template <int EPI>
__global__ __launch_bounds__(256)
void gemm_nt_f32(const float* __restrict__ A, const float* __restrict__ Bm,
                 float* __restrict__ C, int M, int N, int K,
                 int lda, int ldb, int ldc,
                 const float* __restrict__ bias)
{
    constexpr int BM = 128, BN = 128, BK = 16, TM = 8, TN = 8;
    __shared__ float As[BK][BM + 4];
    __shared__ float Bs[BK][BN + 4];

    const int tid = threadIdx.x;
    const int tx  = tid & 15;   // n dir (0..15)
    const int ty  = tid >> 4;   // m dir (0..15)
    const int m0  = blockIdx.y * BM;
    const int n0  = blockIdx.x * BN;

    float acc[TM][TN];
#pragma unroll
    for (int i = 0; i < TM; i++)
#pragma unroll
        for (int j = 0; j < TN; j++) acc[i][j] = 0.f;

    for (int k0 = 0; k0 < K; k0 += BK) {
        float4 av[2], bv[2];
#pragma unroll
        for (int q = 0; q < 2; q++) {
            int lin = tid + q * 256;         // 0..511
            int r   = lin >> 2;              // row in tile 0..127
            int c4  = (lin & 3) * 4;         // k-offset 0,4,8,12
            int gk  = k0 + c4;
            int gm  = m0 + r;
            int gn  = n0 + r;
            av[q] = make_float4(0.f, 0.f, 0.f, 0.f);
            bv[q] = make_float4(0.f, 0.f, 0.f, 0.f);
            if (gm < M && gk < K)
                av[q] = *reinterpret_cast<const float4*>(A + (size_t)gm * lda + gk);
            if (gn < N && gk < K)
                bv[q] = *reinterpret_cast<const float4*>(Bm + (size_t)gn * ldb + gk);
        }
        __syncthreads();
#pragma unroll
        for (int q = 0; q < 2; q++) {
            int lin = tid + q * 256;
            int r   = lin >> 2;
            int c4  = (lin & 3) * 4;
            As[c4 + 0][r] = av[q].x; As[c4 + 1][r] = av[q].y;
            As[c4 + 2][r] = av[q].z; As[c4 + 3][r] = av[q].w;
            Bs[c4 + 0][r] = bv[q].x; Bs[c4 + 1][r] = bv[q].y;
            Bs[c4 + 2][r] = bv[q].z; Bs[c4 + 3][r] = bv[q].w;
        }
        __syncthreads();
#pragma unroll
        for (int k = 0; k < BK; k++) {
            float a[TM], b[TN];
#pragma unroll
            for (int i = 0; i < TM; i++) a[i] = As[k][ty * TM + i];
#pragma unroll
            for (int j = 0; j < TN; j++) b[j] = Bs[k][tx * TN + j];
#pragma unroll
            for (int i = 0; i < TM; i++)
#pragma unroll
                for (int j = 0; j < TN; j++)
                    acc[i][j] = fmaf(a[i], b[j], acc[i][j]);
        }
    }

#pragma unroll
    for (int i = 0; i < TM; i++) {
        int gm = m0 + ty * TM + i;
        if (gm >= M) continue;
#pragma unroll
        for (int j = 0; j < TN; j++) {
            int gn = n0 + tx * TN + j;
            if (gn >= N) continue;
            float v = acc[i][j];
            if (EPI == 1) {
                v += bias[gn];
                v = (v > 20.f) ? v : log1pf(__expf(v));
            }
            C[(size_t)gm * ldc + gn] = v;
        }
    }
}

// ---------------------------------------------------------------------------
// Depthwise causal conv (4 taps) + bias + SiLU, in-place on the xi half of xz.
// One thread per (b, d); rolling window; coalesced over d.
// ---------------------------------------------------------------------------
__global__ __launch_bounds__(256)
void conv_silu_inplace(float* __restrict__ xz,
                       const float* __restrict__ conv_w,
                       const float* __restrict__ conv_b)
{
    int t = blockIdx.x * blockDim.x + threadIdx.x;
    if (t >= Bq * DI) return;
    int b = t / DI, d = t % DI;
    float w0 = conv_w[d * 4 + 0], w1 = conv_w[d * 4 + 1];
    float w2 = conv_w[d * 4 + 2], w3 = conv_w[d * 4 + 3];
    float bias = conv_b[d];
    float xm3 = 0.f, xm2 = 0.f, xm1 = 0.f;
    float* p = xz + (size_t)b * Lq * XZ_LD + d;
    for (int l = 0; l < Lq; l++) {
        float x0 = p[(size_t)l * XZ_LD];
        float v  = fmaf(w3, x0, fmaf(w2, xm1, fmaf(w1, xm2, w0 * xm3))) + bias;
        p[(size_t)l * XZ_LD] = silu_f(v);
        xm3 = xm2; xm2 = xm1; xm1 = x0;
    }
}

// ---------------------------------------------------------------------------
// Selective scan, 3-phase chunked.
// Phase A: per (b,chunk,d): local scan with h=0; emit P[n]=prod dA, S[n]=h_end.
// ---------------------------------------------------------------------------
__global__ __launch_bounds__(256)
void scan_phaseA(const float* __restrict__ xz,
                 const float* __restrict__ dt,
                 const float* __restrict__ xdbl,
                 const float* __restrict__ A_log,
                 float* __restrict__ Pbuf, float* __restrict__ Sbuf)
{
    int t = blockIdx.x * 256 + threadIdx.x;
    if (t >= Bq * NC * DI) return;
    int d = t & (DI - 1);
    int c = (t / DI) & (NC - 1);
    int b = t / (DI * NC);

    float Aar[NST];
#pragma unroll
    for (int n = 0; n < NST; n++) Aar[n] = -__expf(A_log[d * NST + n]);

    float h[NST], P[NST];
#pragma unroll
    for (int n = 0; n < NST; n++) { h[n] = 0.f; P[n] = 1.f; }

    int l0 = c * CL;
    const float* dtp = dt   + ((size_t)(b * Lq + l0)) * DI + d;
    const float* xip = xz   + ((size_t)(b * Lq + l0)) * XZ_LD + d;
    const float* bp  = xdbl + ((size_t)(b * Lq + l0)) * XDBL_LD + DTR;

    for (int l = 0; l < CL; l++) {
        float dtv = dtp[(size_t)l * DI];
        float xiv = xip[(size_t)l * XZ_LD];
        float dx  = dtv * xiv;
        float4 b0 = *reinterpret_cast<const float4*>(bp + (size_t)l * XDBL_LD + 0);
        float4 b1 = *reinterpret_cast<const float4*>(bp + (size_t)l * XDBL_LD + 4);
        float4 b2 = *reinterpret_cast<const float4*>(bp + (size_t)l * XDBL_LD + 8);
        float4 b3 = *reinterpret_cast<const float4*>(bp + (size_t)l * XDBL_LD + 12);
        float barr[NST] = {b0.x,b0.y,b0.z,b0.w, b1.x,b1.y,b1.z,b1.w,
                           b2.x,b2.y,b2.z,b2.w, b3.x,b3.y,b3.z,b3.w};
#pragma unroll
        for (int n = 0; n < NST; n++) {
            float dA = __expf(dtv * Aar[n]);
            h[n] = fmaf(dA, h[n], dx * barr[n]);
            P[n] *= dA;
        }
    }
    size_t base = ((size_t)(b * NC + c) * NST) * DI + d;
#pragma unroll
    for (int n = 0; n < NST; n++) {
        Pbuf[base + (size_t)n * DI] = P[n];
        Sbuf[base + (size_t)n * DI] = h[n];
    }
}

// Phase B: per (b,d): sequentially combine the NC chunks; emit h at chunk entry.
__global__ __launch_bounds__(256)
void scan_phaseB(const float* __restrict__ P, const float* __restrict__ S,
                 float* __restrict__ Hin)
{
    int t = blockIdx.x * blockDim.x + threadIdx.x;
    if (t >= Bq * DI) return;
    int d = t & (DI - 1);
    int b = t / DI;
    float H[NST];
#pragma unroll
    for (int n = 0; n < NST; n++) H[n] = 0.f;
    for (int c = 0; c < NC; c++) {
        size_t base = ((size_t)(b * NC + c) * NST) * DI + d;
#pragma unroll
        for (int n = 0; n < NST; n++) {
            size_t idx = base + (size_t)n * DI;
            Hin[idx] = H[n];
            H[n] = fmaf(P[idx], H[n], S[idx]);
        }
    }
}

// Phase C: replay local scan with proper h_in; y = sum_n h*C + D*xi;
// gated = y * silu(z), written in place into the z half of xz.
__global__ __launch_bounds__(256)
void scan_phaseC(float* __restrict__ xz,
                 const float* __restrict__ dt,
                 const float* __restrict__ xdbl,
                 const float* __restrict__ A_log,
                 const float* __restrict__ Dskip,
                 const float* __restrict__ Hin)
{
    int t = blockIdx.x * 256 + threadIdx.x;
    if (t >= Bq * NC * DI) return;
    int d = t & (DI - 1);
    int c = (t / DI) & (NC - 1);
    int b = t / (DI * NC);

    float Aar[NST];
#pragma unroll
    for (int n = 0; n < NST; n++) Aar[n] = -__expf(A_log[d * NST + n]);

    float h[NST];
    size_t hbase = ((size_t)(b * NC + c) * NST) * DI + d;
#pragma unroll
    for (int n = 0; n < NST; n++) h[n] = Hin[hbase + (size_t)n * DI];

    float Dv = Dskip[d];
    int l0 = c * CL;
    const float* dtp = dt   + ((size_t)(b * Lq + l0)) * DI + d;
    float*       xip = xz   + ((size_t)(b * Lq + l0)) * XZ_LD + d;
    const float* bp  = xdbl + ((size_t)(b * Lq + l0)) * XDBL_LD + DTR;

    for (int l = 0; l < CL; l++) {
        float dtv = dtp[(size_t)l * DI];
        float xiv = xip[(size_t)l * XZ_LD];
        float dx  = dtv * xiv;
        const float* row = bp + (size_t)l * XDBL_LD;
        float4 b0 = *reinterpret_cast<const float4*>(row + 0);
        float4 b1 = *reinterpret_cast<const float4*>(row + 4);
        float4 b2 = *reinterpret_cast<const float4*>(row + 8);
        float4 b3 = *reinterpret_cast<const float4*>(row + 12);
        float barr[NST] = {b0.x,b0.y,b0.z,b0.w, b1.x,b1.y,b1.z,b1.w,
                           b2.x,b2.y,b2.z,b2.w, b3.x,b3.y,b3.z,b3.w};
        float4 c0 = *reinterpret_cast<const float4*>(row + 16);
        float4 c1 = *reinterpret_cast<const float4*>(row + 20);
        float4 c2 = *reinterpret_cast<const float4*>(row + 24);
        float4 c3 = *reinterpret_cast<const float4*>(row + 28);
        float carr[NST] = {c0.x,c0.y,c0.z,c0.w, c1.x,c1.y,c1.z,c1.w,
                           c2.x,c2.y,c2.z,c2.w, c3.x,c3.y,c3.z,c3.w};
        float y = 0.f;
#pragma unroll
        for (int n = 0; n < NST; n++) {
            float dA = __expf(dtv * Aar[n]);
            h[n] = fmaf(dA, h[n], dx * barr[n]);
            y = fmaf(h[n], carr[n], y);
        }
        y = fmaf(Dv, xiv, y);
        float z = xip[(size_t)l * XZ_LD + DI];   // z half
        xip[(size_t)l * XZ_LD + DI] = y * silu_f(z);
    }
}

// ---------------------------------------------------------------------------
extern "C" void kernel_launch(void* const* d_in, const int* in_sizes, int n_in,
                              void* d_out, int out_size, void* d_ws, size_t ws_size,
                              hipStream_t stream)
{
    const float* x      = (const float*)d_in[0];
    const float* W_in   = (const float*)d_in[1];
    const float* conv_w = (const float*)d_in[2];
    const float* conv_b = (const float*)d_in[3];
    const float* W_x    = (const float*)d_in[4];
    const float* W_dt   = (const float*)d_in[5];
    const float* b_dt   = (const float*)d_in[6];
    const float* W_out  = (const float*)d_in[7];
    const float* A_log  = (const float*)d_in[8];
    const float* D_skip = (const float*)d_in[9];
    float* out = (float*)d_out;

    float* ws   = (float*)d_ws;
    float* xz   = ws + OFF_XZ;
    float* xdbl = ws + OFF_XDBL;
    float* dt   = ws + OFF_DT;
    float* Pb   = ws + OFF_P;
    float* Sb   = ws + OFF_S;
    float* Hin  = ws + OFF_H;

    dim3 blk(256);

    // 1) xz = x @ W_in.T   (M=4096, N=4096, K=1024)
    {
        dim3 grid((2 * DI + 127) / 128, (M_ROWS + 127) / 128);
        gemm_nt_f32<0><<<grid, blk, 0, stream>>>(x, W_in, xz,
            M_ROWS, 2 * DI, Dq, Dq, Dq, XZ_LD, nullptr);
    }
    // 2) causal depthwise conv + silu (in place on xi half)
    conv_silu_inplace<<<dim3((Bq * DI + 255) / 256), blk, 0, stream>>>(xz, conv_w, conv_b);

    // 3) x_dbl = xi @ W_x.T  (M=4096, N=96, K=2048); xi has lda=4096
    {
        dim3 grid((XDBL_LD + 127) / 128, (M_ROWS + 127) / 128);
        gemm_nt_f32<0><<<grid, blk, 0, stream>>>(xz, W_x, xdbl,
            M_ROWS, XDBL_LD, DI, XZ_LD, DI, XDBL_LD, nullptr);
    }
    // 4) dt = softplus(x_dbl[:, :64] @ W_dt.T + b_dt)  (M=4096, N=2048, K=64)
    {
        dim3 grid((DI + 127) / 128, (M_ROWS + 127) / 128);
        gemm_nt_f32<1><<<grid, blk, 0, stream>>>(xdbl, W_dt, dt,
            M_ROWS, DI, DTR, XDBL_LD, DTR, DI, b_dt);
    }
    // 5) selective scan (3-phase) + gating fused into phase C
    scan_phaseA<<<dim3(Bq * NC * DI / 256), blk, 0, stream>>>(xz, dt, xdbl, A_log, Pb, Sb);
    scan_phaseB<<<dim3((Bq * DI + 255) / 256), blk, 0, stream>>>(Pb, Sb, Hin);
    scan_phaseC<<<dim3(Bq * NC * DI / 256), blk, 0, stream>>>(xz, dt, xdbl, A_log, D_skip, Hin);

    // 6) out = gated @ W_out.T  (M=4096, N=1024, K=2048); gated at xz+DI, lda=4096
    {
        dim3 grid((Dq + 127) / 128, (M_ROWS + 127) / 128);
        gemm_nt_f32<0><<<grid, blk, 0, stream>>>(xz + DI, W_out, out,
            M_ROWS, Dq, DI, XZ_LD, DI, Dq, nullptr);
    }
}

// Round 3
// 546.581 us; speedup vs baseline: 2.9612x; 2.9612x over previous
//
#include <hip/hip_runtime.h>
#include <math.h>

typedef float          floatx4  __attribute__((ext_vector_type(4)));
typedef unsigned int   uintx4   __attribute__((ext_vector_type(4)));
typedef unsigned short ushortx4 __attribute__((ext_vector_type(4)));
typedef unsigned short u16;

constexpr int Bq  = 2;
constexpr int Lq  = 2048;
constexpr int Dq  = 1024;
constexpr int DI  = 2048;
constexpr int DTR = 64;
constexpr int NST = 16;
constexpr int MR  = Bq * Lq;          // 4096
constexpr int NC  = 16;               // scan chunks
constexpr int CL  = Lq / NC;          // 128

// ---------------- workspace layout (f32 words) — total ~113 MB ----------------
constexpr size_t NWB     = (size_t)MR * DI;          // 8,388,608
constexpr size_t W_XIPRE = 0;                        // xi_pre; later dt (MR x DI f32)
constexpr size_t W_Z     = NWB;                      // z (MR x DI f32)
constexpr size_t W_XDBL  = 2 * NWB;                  // MR x 96 f32
constexpr size_t SZ_XDBL = (size_t)MR * 96;
constexpr size_t SZ_PS   = (size_t)Bq * NC * NST * DI;   // 1,048,576 f32
constexpr size_t W_PB    = W_XDBL + SZ_XDBL;         // P; later W_out hi (exactly fits)
constexpr size_t W_SB    = W_PB + SZ_PS;             // S/Hin; later W_out lo (exactly fits)
constexpr size_t W_R1    = W_SB + SZ_PS;             // 8,388,608 f32 split region
constexpr size_t W_SM    = W_R1 + NWB;               // small splits
// small-split offsets in u16 units from (u16*)(ws + W_SM):
constexpr size_t U_DTH = 0, U_DTL = 262144, U_WDTH = 524288, U_WDTL = 655360,
                 U_WXH = 786432, U_WXL = 983040;

__device__ __forceinline__ u16 f2b(float x) {            // f32 -> bf16 RNE
    unsigned int u = __float_as_uint(x);
    u += 0x7fffu + ((u >> 16) & 1u);
    return (u16)(u >> 16);
}
__device__ __forceinline__ float b2f(u16 h) { return __uint_as_float(((unsigned int)h) << 16); }
__device__ __forceinline__ float silu_f(float x) { return x / (1.f + __expf(-x)); }

__device__ __forceinline__ void mfma16(floatx4& d, uintx4 a, uintx4 b) {
    asm("v_mfma_f32_16x16x32_bf16 %0, %1, %2, %0" : "+v"(d) : "v"(a), "v"(b));
}
__device__ __forceinline__ void gload16(const void* g, void* l) {
    __builtin_amdgcn_global_load_lds((const __attribute__((address_space(1))) void*)g,
                                     (__attribute__((address_space(3))) void*)l, 16, 0, 0);
}

// ---------------------------------------------------------------------------
// split f32 -> bf16 hi/lo (vectorized x4)
// ---------------------------------------------------------------------------
__global__ __launch_bounds__(256)
void split_bf16(const float* __restrict__ src, u16* __restrict__ hi,
                u16* __restrict__ lo, int n4)
{
    int t = blockIdx.x * 256 + threadIdx.x;
    if (t >= n4) return;
    floatx4 v = ((const floatx4*)src)[t];
    ushortx4 h, l;
#pragma unroll
    for (int i = 0; i < 4; i++) {
        h[i] = f2b(v[i]);
        l[i] = f2b(v[i] - b2f(h[i]));
    }
    ((ushortx4*)hi)[t] = h;
    ((ushortx4*)lo)[t] = l;
}

// extract + split cols 0..63 of xdbl (ld 96) into dense (ld 64) hi/lo
__global__ __launch_bounds__(256)
void split_dtin(const float* __restrict__ xdbl, u16* __restrict__ hi, u16* __restrict__ lo)
{
    int t = blockIdx.x * 256 + threadIdx.x;      // MR*16
    if (t >= MR * 16) return;
    int r = t >> 4, c4 = (t & 15) * 4;
    floatx4 v = *(const floatx4*)(xdbl + (size_t)r * 96 + c4);
    ushortx4 h, l;
#pragma unroll
    for (int i = 0; i < 4; i++) { h[i] = f2b(v[i]); l[i] = f2b(v[i] - b2f(h[i])); }
    *(ushortx4*)(hi + (size_t)r * 64 + c4) = h;
    *(ushortx4*)(lo + (size_t)r * 64 + c4) = l;
}

// ---------------------------------------------------------------------------
// Split-bf16 MFMA GEMM:  C[m,n] = sum_k A[m,k]*B[n,k]  (both K-major)
// A ~ (Ah+Al), B ~ (Bh+Bl); 3 MFMAs per fragment pair.
// BM=WM*FM*16, BN=WN*FN*16, BK=32, 4 waves (256 thr).
// EPI: 0 plain, 1 bias+softplus, 2 split-dest (col<nsplit -> C else C2, ld=nsplit)
// ---------------------------------------------------------------------------
__device__ __forceinline__ void stage_tile(const u16* g, u16* s, int rows, int ld,
                                           int k0, int wave, int lane)
{
    const int chunks = rows * 4;                 // 16B chunks (row = 32 bf16 = 64B)
    for (int c0 = wave * 64; c0 < chunks; c0 += 256) {
        int c = c0 + lane;
        const u16* gp = g + (size_t)(c >> 2) * ld + k0 + (c & 3) * 8;
        u16* sp = s + (size_t)c0 * 8;            // wave-uniform base; HW adds lane*16B
        gload16(gp, sp);
    }
}

template <int WM, int WN, int FM, int FN, int EPI>
__global__ __launch_bounds__(256)
void gemm_split(const u16* __restrict__ Ah, const u16* __restrict__ Al,
                const u16* __restrict__ Bh, const u16* __restrict__ Bl,
                float* __restrict__ C, float* __restrict__ C2,
                const float* __restrict__ bias,
                int M, int N, int K, int lda, int ldb, int ldc, int nsplit)
{
    constexpr int BM = WM * FM * 16, BN = WN * FN * 16, BK = 32;
    __shared__ u16 sm[(2 * BM + 2 * BN) * BK];
    u16* sAh = sm;
    u16* sAl = sm + BM * BK;
    u16* sBh = sm + 2 * BM * BK;
    u16* sBl = sm + 2 * BM * BK + BN * BK;

    const int tid = threadIdx.x, lane = tid & 63, wave = tid >> 6;
    const int wm = wave % WM, wn = wave / WM;
    const long m0 = (long)blockIdx.y * BM, n0 = (long)blockIdx.x * BN;
    const int frk = (lane >> 4) * 8;             // k-offset within fragment
    const int frr = lane & 15;                   // row within 16

    floatx4 acc[FM][FN];
#pragma unroll
    for (int i = 0; i < FM; i++)
#pragma unroll
        for (int j = 0; j < FN; j++) acc[i][j] = (floatx4){0.f, 0.f, 0.f, 0.f};

    const u16* gAh = Ah + (size_t)m0 * lda;
    const u16* gAl = Al + (size_t)m0 * lda;
    const u16* gBh = Bh + (size_t)n0 * ldb;
    const u16* gBl = Bl + (size_t)n0 * ldb;

    for (int k0 = 0; k0 < K; k0 += BK) {
        stage_tile(gAh, sAh, BM, lda, k0, wave, lane);
        stage_tile(gAl, sAl, BM, lda, k0, wave, lane);
        stage_tile(gBh, sBh, BN, ldb, k0, wave, lane);
        stage_tile(gBl, sBl, BN, ldb, k0, wave, lane);
        __syncthreads();                          // drains vmcnt for gload_lds

        uintx4 ah[FM], al2[FM], bh[FN], bl2[FN];
#pragma unroll
        for (int f = 0; f < FM; f++) {
            int r = (wm * FM + f) * 16 + frr;
            ah[f]  = *(const uintx4*)(sAh + r * 32 + frk);
            al2[f] = *(const uintx4*)(sAl + r * 32 + frk);
        }
#pragma unroll
        for (int f = 0; f < FN; f++) {
            int r = (wn * FN + f) * 16 + frr;
            bh[f]  = *(const uintx4*)(sBh + r * 32 + frk);
            bl2[f] = *(const uintx4*)(sBl + r * 32 + frk);
        }
#pragma unroll
        for (int fm = 0; fm < FM; fm++)
#pragma unroll
            for (int fn = 0; fn < FN; fn++) {
                mfma16(acc[fm][fn], ah[fm], bh[fn]);
                mfma16(acc[fm][fn], ah[fm], bl2[fn]);
                mfma16(acc[fm][fn], al2[fm], bh[fn]);
            }
        __syncthreads();
    }

#pragma unroll
    for (int fm = 0; fm < FM; fm++) {
        long row0 = m0 + (wm * FM + fm) * 16 + ((lane >> 4) << 2);
#pragma unroll
        for (int fn = 0; fn < FN; fn++) {
            long col = n0 + (wn * FN + fn) * 16 + (lane & 15);
#pragma unroll
            for (int i = 0; i < 4; i++) {
                long row = row0 + i;
                float v = acc[fm][fn][i];
                if constexpr (EPI == 1) {
                    v += bias[col];
                    v = (v > 20.f) ? v : log1pf(__expf(v));
                    C[row * (long)ldc + col] = v;
                } else if constexpr (EPI == 2) {
                    if (col < nsplit) C[row * (long)nsplit + col] = v;
                    else              C2[row * (long)nsplit + (col - nsplit)] = v;
                } else {
                    C[row * (long)ldc + col] = v;
                }
            }
        }
    }
}

// ---------------------------------------------------------------------------
// depthwise causal conv(4) + bias + SiLU; writes xi as bf16 hi/lo split.
// thread per (b, l, d4); fully parallel (reads xi_pre, separate output).
// ---------------------------------------------------------------------------
__global__ __launch_bounds__(256)
void conv_silu_split(const float* __restrict__ xi_pre, const float* __restrict__ cw,
                     const float* __restrict__ cb, u16* __restrict__ xih,
                     u16* __restrict__ xil)
{
    int t = blockIdx.x * 256 + threadIdx.x;      // B*L*512
    int d4 = (t & 511) * 4;
    int l  = (t >> 9) & (Lq - 1);
    int b  = t >> 20;
    const float* base = xi_pre + ((size_t)b * Lq) * DI + d4;
    floatx4 w0 = *(const floatx4*)(cw + (size_t)(d4 + 0) * 4);
    floatx4 w1 = *(const floatx4*)(cw + (size_t)(d4 + 1) * 4);
    floatx4 w2 = *(const floatx4*)(cw + (size_t)(d4 + 2) * 4);
    floatx4 w3 = *(const floatx4*)(cw + (size_t)(d4 + 3) * 4);
    floatx4 o  = *(const floatx4*)(cb + d4);
#pragma unroll
    for (int j = 0; j < 4; j++) {
        int ls = l - 3 + j;
        if (ls < 0) continue;
        floatx4 xv = *(const floatx4*)(base + (size_t)ls * DI);
        o[0] = fmaf(w0[j], xv[0], o[0]);
        o[1] = fmaf(w1[j], xv[1], o[1]);
        o[2] = fmaf(w2[j], xv[2], o[2]);
        o[3] = fmaf(w3[j], xv[3], o[3]);
    }
    size_t oidx = ((size_t)b * Lq + l) * DI + d4;
    ushortx4 h, lo;
#pragma unroll
    for (int i = 0; i < 4; i++) {
        float v = silu_f(o[i]);
        h[i]  = f2b(v);
        lo[i] = f2b(v - b2f(h[i]));
    }
    *(ushortx4*)(xih + oidx) = h;
    *(ushortx4*)(xil + oidx) = lo;
}

// ---------------------------------------------------------------------------
// selective scan, 3-phase chunked (NC chunks of CL)
// ---------------------------------------------------------------------------
__global__ __launch_bounds__(256)
void scanA(const u16* __restrict__ xih, const u16* __restrict__ xil,
           const float* __restrict__ dt, const float* __restrict__ xdbl,
           const float* __restrict__ A_log, float* __restrict__ P, float* __restrict__ S)
{
    int t = blockIdx.x * 256 + threadIdx.x;      // B*NC*DI = 65536
    int d = t & (DI - 1);
    int c = (t >> 11) & (NC - 1);
    int b = t >> 15;

    float Aar[NST];
    const floatx4* ap = (const floatx4*)(A_log + (size_t)d * NST);
#pragma unroll
    for (int q = 0; q < 4; q++) {
        floatx4 av = ap[q];
#pragma unroll
        for (int i = 0; i < 4; i++) Aar[q * 4 + i] = -__expf(av[i]);
    }
    float h[NST], Pr[NST];
#pragma unroll
    for (int n = 0; n < NST; n++) { h[n] = 0.f; Pr[n] = 1.f; }

    int l0 = c * CL;
    size_t xbase = ((size_t)b * Lq + l0) * DI + d;
    size_t rbase = ((size_t)b * Lq + l0) * 96;
    for (int l = 0; l < CL; l++) {
        size_t xi_ = xbase + (size_t)l * DI;
        float dtv = dt[xi_];
        float xiv = b2f(xih[xi_]) + b2f(xil[xi_]);
        float dx  = dtv * xiv;
        const floatx4* bp = (const floatx4*)(xdbl + rbase + (size_t)l * 96 + DTR);
        float Bv[NST];
#pragma unroll
        for (int q = 0; q < 4; q++) {
            floatx4 v = bp[q];
#pragma unroll
            for (int i = 0; i < 4; i++) Bv[q * 4 + i] = v[i];
        }
#pragma unroll
        for (int n = 0; n < NST; n++) {
            float dA = __expf(dtv * Aar[n]);
            h[n] = fmaf(dA, h[n], dx * Bv[n]);
            Pr[n] *= dA;
        }
    }
    size_t obase = ((size_t)(b * NC + c) * NST) * DI + d;
#pragma unroll
    for (int n = 0; n < NST; n++) {
        P[obase + (size_t)n * DI] = Pr[n];
        S[obase + (size_t)n * DI] = h[n];
    }
}

// NOTE: S and Hin may alias (element-wise read-before-write) — no __restrict__.
__global__ __launch_bounds__(256)
void scanB(const float* P, const float* S, float* Hin)
{
    int t = blockIdx.x * 256 + threadIdx.x;
    if (t >= Bq * DI) return;
    int d = t & (DI - 1);
    int b = t >> 11;
    float H[NST];
#pragma unroll
    for (int n = 0; n < NST; n++) H[n] = 0.f;
    for (int c = 0; c < NC; c++) {
        size_t base = ((size_t)(b * NC + c) * NST) * DI + d;
#pragma unroll
        for (int n = 0; n < NST; n++) {
            size_t idx = base + (size_t)n * DI;
            float p = P[idx];
            float s = S[idx];
            Hin[idx] = H[n];
            H[n] = fmaf(p, H[n], s);
        }
    }
}

// reads xi-split at [idx], writes gated-split at [idx] (same buffers — elementwise safe)
__global__ __launch_bounds__(256)
void scanC(u16* xgh, u16* xgl,
           const float* __restrict__ dt, const float* __restrict__ xdbl,
           const float* __restrict__ A_log, const float* __restrict__ Dsk,
           const float* __restrict__ Hin, const float* __restrict__ z)
{
    int t = blockIdx.x * 256 + threadIdx.x;
    int d = t & (DI - 1);
    int c = (t >> 11) & (NC - 1);
    int b = t >> 15;

    float Aar[NST];
    const floatx4* ap = (const floatx4*)(A_log + (size_t)d * NST);
#pragma unroll
    for (int q = 0; q < 4; q++) {
        floatx4 av = ap[q];
#pragma unroll
        for (int i = 0; i < 4; i++) Aar[q * 4 + i] = -__expf(av[i]);
    }
    float h[NST];
    size_t hbase = ((size_t)(b * NC + c) * NST) * DI + d;
#pragma unroll
    for (int n = 0; n < NST; n++) h[n] = Hin[hbase + (size_t)n * DI];

    float Dv = Dsk[d];
    int l0 = c * CL;
    size_t xbase = ((size_t)b * Lq + l0) * DI + d;
    size_t rbase = ((size_t)b * Lq + l0) * 96;
    for (int l = 0; l < CL; l++) {
        size_t xi_ = xbase + (size_t)l * DI;
        float dtv = dt[xi_];
        float xiv = b2f(xgh[xi_]) + b2f(xgl[xi_]);
        float dx  = dtv * xiv;
        const floatx4* rp = (const floatx4*)(xdbl + rbase + (size_t)l * 96 + DTR);
        float Bv[NST], Cv[NST];
#pragma unroll
        for (int q = 0; q < 4; q++) {
            floatx4 v = rp[q];
            floatx4 w = rp[q + 4];
#pragma unroll
            for (int i = 0; i < 4; i++) { Bv[q * 4 + i] = v[i]; Cv[q * 4 + i] = w[i]; }
        }
        float y = 0.f;
#pragma unroll
        for (int n = 0; n < NST; n++) {
            float dA = __expf(dtv * Aar[n]);
            h[n] = fmaf(dA, h[n], dx * Bv[n]);
            y = fmaf(h[n], Cv[n], y);
        }
        y = fmaf(Dv, xiv, y);
        float zv = z[xi_];
        float g = y * silu_f(zv);
        u16 gh = f2b(g);
        xgh[xi_] = gh;
        xgl[xi_] = f2b(g - b2f(gh));
    }
}

// ---------------------------------------------------------------------------
extern "C" void kernel_launch(void* const* d_in, const int* in_sizes, int n_in,
                              void* d_out, int out_size, void* d_ws, size_t ws_size,
                              hipStream_t stream)
{
    const float* x      = (const float*)d_in[0];
    const float* W_in   = (const float*)d_in[1];
    const float* conv_w = (const float*)d_in[2];
    const float* conv_b = (const float*)d_in[3];
    const float* W_x    = (const float*)d_in[4];
    const float* W_dt   = (const float*)d_in[5];
    const float* b_dt   = (const float*)d_in[6];
    const float* W_out  = (const float*)d_in[7];
    const float* A_log  = (const float*)d_in[8];
    const float* D_skip = (const float*)d_in[9];
    float* out = (float*)d_out;

    float* ws     = (float*)d_ws;
    float* xi_pre = ws + W_XIPRE;        // later reused as dt
    float* dt     = xi_pre;
    float* z      = ws + W_Z;
    float* xdbl   = ws + W_XDBL;
    float* Pb     = ws + W_PB;
    float* Sb     = ws + W_SB;           // also Hin (aliased in scanB)
    u16* r1  = (u16*)(ws + W_R1);
    u16* xhi = r1, *xlo = r1 + 4194304, *winh = r1 + 8388608, *winl = r1 + 12582912;
    u16* xih = r1, *xil = r1 + 8388608;  // phase2: xi split; phase3: gated split
    u16* smal = (u16*)(ws + W_SM);
    u16* dth = smal + U_DTH,  *dtl = smal + U_DTL;
    u16* wdth = smal + U_WDTH, *wdtl = smal + U_WDTL;
    u16* wxh = smal + U_WXH,  *wxl = smal + U_WXL;
    // W_out split: hi fills ALL of Pb (dead after scanB), lo fills ALL of Sb
    // (dead after scanC). Split launched only AFTER scanC (fixes r2 aliasing bug).
    u16* wouth = (u16*)Pb, *woutl = (u16*)Sb;

    // 1) split x, W_in
    split_bf16<<<4096, 256, 0, stream>>>(x, xhi, xlo, 1048576);
    split_bf16<<<4096, 256, 0, stream>>>(W_in, winh, winl, 1048576);
    // 2) xz = x @ W_in.T  -> xi_pre | z   (M=4096, N=4096, K=1024)
    gemm_split<2, 2, 4, 4, 2><<<dim3(32, 32), 256, 0, stream>>>(
        xhi, xlo, winh, winl, xi_pre, z, nullptr, MR, 4096, Dq, Dq, Dq, 2048, 2048);
    // 3) conv + silu -> xi split (overwrites phase1 splits; GEMM1 already consumed)
    conv_silu_split<<<8192, 256, 0, stream>>>(xi_pre, conv_w, conv_b, xih, xil);
    // 4) x_dbl = xi @ W_x.T   (M=4096, N=96, K=2048), BM=64 BN=32
    split_bf16<<<192, 256, 0, stream>>>(W_x, wxh, wxl, 49152);
    gemm_split<2, 2, 2, 1, 0><<<dim3(3, 64), 256, 0, stream>>>(
        xih, xil, wxh, wxl, xdbl, nullptr, nullptr, MR, 96, DI, DI, DI, 96, 0);
    // 5) dt = softplus(x_dbl[:, :64] @ W_dt.T + b_dt)  (M=4096, N=2048, K=64)
    split_dtin<<<256, 256, 0, stream>>>(xdbl, dth, dtl);
    split_bf16<<<128, 256, 0, stream>>>(W_dt, wdth, wdtl, 32768);
    gemm_split<2, 2, 4, 4, 1><<<dim3(16, 32), 256, 0, stream>>>(
        dth, dtl, wdth, wdtl, dt, nullptr, b_dt, MR, DI, DTR, DTR, DTR, DI, 0);
    // 6) selective scan (3-phase) + gating; gated written as bf16 split into r1
    scanA<<<256, 256, 0, stream>>>(xih, xil, dt, xdbl, A_log, Pb, Sb);
    scanB<<<16, 256, 0, stream>>>(Pb, Sb, Sb);
    scanC<<<256, 256, 0, stream>>>(xih, xil, dt, xdbl, A_log, D_skip, Sb, z);
    // 7) split W_out AFTER scanC (Pb and Sb both dead now), then final GEMM
    split_bf16<<<2048, 256, 0, stream>>>(W_out, wouth, woutl, 524288);
    gemm_split<2, 2, 4, 4, 0><<<dim3(8, 32), 256, 0, stream>>>(
        xih, xil, wouth, woutl, out, nullptr, nullptr, MR, Dq, DI, DI, DI, Dq, 0);
}

// Round 4
// 534.832 us; speedup vs baseline: 3.0262x; 1.0220x over previous
//
#include <hip/hip_runtime.h>
#include <math.h>

typedef float          floatx4  __attribute__((ext_vector_type(4)));
typedef unsigned int   uintx4   __attribute__((ext_vector_type(4)));
typedef unsigned short ushortx4 __attribute__((ext_vector_type(4)));
typedef unsigned short u16;

constexpr int Bq  = 2;
constexpr int Lq  = 2048;
constexpr int Dq  = 1024;
constexpr int DI  = 2048;
constexpr int DTR = 64;
constexpr int NST = 16;
constexpr int MR  = Bq * Lq;          // 4096
constexpr int NC  = 16;               // scan chunks
constexpr int CL  = Lq / NC;          // 128

// ---------------- workspace layout (f32 words) — total ~113 MB ----------------
constexpr size_t NWB     = (size_t)MR * DI;          // 8,388,608
constexpr size_t W_XIPRE = 0;                        // xi_pre; later dt (MR x DI f32)
constexpr size_t W_Z     = NWB;                      // z (MR x DI f32)
constexpr size_t W_XDBL  = 2 * NWB;                  // MR x 96 f32
constexpr size_t SZ_XDBL = (size_t)MR * 96;
constexpr size_t SZ_PS   = (size_t)Bq * NC * NST * DI;   // 1,048,576 f32
constexpr size_t W_PB    = W_XDBL + SZ_XDBL;         // P; later W_out hi (exactly fits)
constexpr size_t W_SB    = W_PB + SZ_PS;             // S/Hin; later W_out lo (exactly fits)
constexpr size_t W_R1    = W_SB + SZ_PS;             // 8,388,608 f32 split region
constexpr size_t W_SM    = W_R1 + NWB;               // small splits
// small-split offsets in u16 units from (u16*)(ws + W_SM):
constexpr size_t U_DTH = 0, U_DTL = 262144, U_WDTH = 524288, U_WDTL = 655360,
                 U_WXH = 786432, U_WXL = 983040;

__device__ __forceinline__ u16 f2b(float x) {            // f32 -> bf16 RNE
    unsigned int u = __float_as_uint(x);
    u += 0x7fffu + ((u >> 16) & 1u);
    return (u16)(u >> 16);
}
__device__ __forceinline__ float b2f(u16 h) { return __uint_as_float(((unsigned int)h) << 16); }
__device__ __forceinline__ float silu_f(float x) { return x / (1.f + __expf(-x)); }

__device__ __forceinline__ void mfma16(floatx4& d, uintx4 a, uintx4 b) {
    asm("v_mfma_f32_16x16x32_bf16 %0, %1, %2, %0" : "+v"(d) : "v"(a), "v"(b));
}
__device__ __forceinline__ void gload16(const void* g, void* l) {
    __builtin_amdgcn_global_load_lds((const __attribute__((address_space(1))) void*)g,
                                     (__attribute__((address_space(3))) void*)l, 16, 0, 0);
}

// ---------------------------------------------------------------------------
// splits
// ---------------------------------------------------------------------------
__device__ __forceinline__ void split_store(const floatx4 v, u16* hi, u16* lo, size_t t) {
    ushortx4 h, l;
#pragma unroll
    for (int i = 0; i < 4; i++) {
        h[i] = f2b(v[i]);
        l[i] = f2b(v[i] - b2f(h[i]));
    }
    ((ushortx4*)hi)[t] = h;
    ((ushortx4*)lo)[t] = l;
}

__global__ __launch_bounds__(256)
void split_bf16(const float* __restrict__ src, u16* __restrict__ hi,
                u16* __restrict__ lo, int n4)
{
    int t = blockIdx.x * 256 + threadIdx.x;
    if (t >= n4) return;
    split_store(((const floatx4*)src)[t], hi, lo, t);
}

// fused two-tensor split
__global__ __launch_bounds__(256)
void split_bf16_x2(const float* __restrict__ s1, u16* __restrict__ h1,
                   u16* __restrict__ l1, int n1,
                   const float* __restrict__ s2, u16* __restrict__ h2,
                   u16* __restrict__ l2, int n2)
{
    int t = blockIdx.x * 256 + threadIdx.x;
    if (t < n1) {
        split_store(((const floatx4*)s1)[t], h1, l1, t);
    } else if (t < n1 + n2) {
        int u = t - n1;
        split_store(((const floatx4*)s2)[u], h2, l2, u);
    }
}

// extract + split cols 0..63 of xdbl (ld 96) into dense (ld 64) hi/lo
__global__ __launch_bounds__(256)
void split_dtin(const float* __restrict__ xdbl, u16* __restrict__ hi, u16* __restrict__ lo)
{
    int t = blockIdx.x * 256 + threadIdx.x;      // MR*16
    if (t >= MR * 16) return;
    int r = t >> 4, c4 = (t & 15) * 4;
    floatx4 v = *(const floatx4*)(xdbl + (size_t)r * 96 + c4);
    ushortx4 h, l;
#pragma unroll
    for (int i = 0; i < 4; i++) { h[i] = f2b(v[i]); l[i] = f2b(v[i] - b2f(h[i])); }
    *(ushortx4*)(hi + (size_t)r * 64 + c4) = h;
    *(ushortx4*)(lo + (size_t)r * 64 + c4) = l;
}

__global__ __launch_bounds__(256)
void zero_f32(float* __restrict__ p, int n4)
{
    int t = blockIdx.x * 256 + threadIdx.x;
    if (t < n4) ((floatx4*)p)[t] = (floatx4){0.f, 0.f, 0.f, 0.f};
}

// ---------------------------------------------------------------------------
// Split-bf16 MFMA GEMM:  C[m,n] = sum_k A[m,k]*B[n,k]  (both K-major)
// A ~ (Ah+Al), B ~ (Bh+Bl); 3 MFMAs per fragment pair.
// BM=WM*FM*16, BN=WN*FN*16, BK=32, 4 waves (256 thr).
// blockIdx.z splits K (each z-slice does K/gridDim.z; EPI must be 3 if z>1).
// EPI: 0 plain, 1 bias+softplus, 2 split-dest, 3 atomicAdd (needs zeroed C)
// ---------------------------------------------------------------------------
__device__ __forceinline__ void stage_tile(const u16* g, u16* s, int rows, int ld,
                                           int k0, int wave, int lane)
{
    const int chunks = rows * 4;                 // 16B chunks (row = 32 bf16 = 64B)
    for (int c0 = wave * 64; c0 < chunks; c0 += 256) {
        int c = c0 + lane;
        const u16* gp = g + (size_t)(c >> 2) * ld + k0 + (c & 3) * 8;
        u16* sp = s + (size_t)c0 * 8;            // wave-uniform base; HW adds lane*16B
        gload16(gp, sp);
    }
}

template <int WM, int WN, int FM, int FN, int EPI>
__global__ __launch_bounds__(256)
void gemm_split(const u16* __restrict__ Ah, const u16* __restrict__ Al,
                const u16* __restrict__ Bh, const u16* __restrict__ Bl,
                float* __restrict__ C, float* __restrict__ C2,
                const float* __restrict__ bias,
                int M, int N, int K, int lda, int ldb, int ldc, int nsplit)
{
    constexpr int BM = WM * FM * 16, BN = WN * FN * 16, BK = 32;
    __shared__ u16 sm[(2 * BM + 2 * BN) * BK];
    u16* sAh = sm;
    u16* sAl = sm + BM * BK;
    u16* sBh = sm + 2 * BM * BK;
    u16* sBl = sm + 2 * BM * BK + BN * BK;

    const int tid = threadIdx.x, lane = tid & 63, wave = tid >> 6;
    const int wm = wave % WM, wn = wave / WM;
    const long m0 = (long)blockIdx.y * BM, n0 = (long)blockIdx.x * BN;
    const int frk = (lane >> 4) * 8;             // k-offset within fragment
    const int frr = lane & 15;                   // row within 16

    const int kchunk = K / gridDim.z;
    const int kBeg = blockIdx.z * kchunk;
    const int kEnd = kBeg + kchunk;

    floatx4 acc[FM][FN];
#pragma unroll
    for (int i = 0; i < FM; i++)
#pragma unroll
        for (int j = 0; j < FN; j++) acc[i][j] = (floatx4){0.f, 0.f, 0.f, 0.f};

    const u16* gAh = Ah + (size_t)m0 * lda;
    const u16* gAl = Al + (size_t)m0 * lda;
    const u16* gBh = Bh + (size_t)n0 * ldb;
    const u16* gBl = Bl + (size_t)n0 * ldb;

    for (int k0 = kBeg; k0 < kEnd; k0 += BK) {
        stage_tile(gAh, sAh, BM, lda, k0, wave, lane);
        stage_tile(gAl, sAl, BM, lda, k0, wave, lane);
        stage_tile(gBh, sBh, BN, ldb, k0, wave, lane);
        stage_tile(gBl, sBl, BN, ldb, k0, wave, lane);
        __syncthreads();                          // drains vmcnt for gload_lds

        uintx4 ah[FM], al2[FM], bh[FN], bl2[FN];
#pragma unroll
        for (int f = 0; f < FM; f++) {
            int r = (wm * FM + f) * 16 + frr;
            ah[f]  = *(const uintx4*)(sAh + r * 32 + frk);
            al2[f] = *(const uintx4*)(sAl + r * 32 + frk);
        }
#pragma unroll
        for (int f = 0; f < FN; f++) {
            int r = (wn * FN + f) * 16 + frr;
            bh[f]  = *(const uintx4*)(sBh + r * 32 + frk);
            bl2[f] = *(const uintx4*)(sBl + r * 32 + frk);
        }
#pragma unroll
        for (int fm = 0; fm < FM; fm++)
#pragma unroll
            for (int fn = 0; fn < FN; fn++) {
                mfma16(acc[fm][fn], ah[fm], bh[fn]);
                mfma16(acc[fm][fn], ah[fm], bl2[fn]);
                mfma16(acc[fm][fn], al2[fm], bh[fn]);
            }
        __syncthreads();
    }

#pragma unroll
    for (int fm = 0; fm < FM; fm++) {
        long row0 = m0 + (wm * FM + fm) * 16 + ((lane >> 4) << 2);
#pragma unroll
        for (int fn = 0; fn < FN; fn++) {
            long col = n0 + (wn * FN + fn) * 16 + (lane & 15);
#pragma unroll
            for (int i = 0; i < 4; i++) {
                long row = row0 + i;
                float v = acc[fm][fn][i];
                if constexpr (EPI == 1) {
                    v += bias[col];
                    v = (v > 20.f) ? v : log1pf(__expf(v));
                    C[row * (long)ldc + col] = v;
                } else if constexpr (EPI == 2) {
                    if (col < nsplit) C[row * (long)nsplit + col] = v;
                    else              C2[row * (long)nsplit + (col - nsplit)] = v;
                } else if constexpr (EPI == 3) {
                    atomicAdd(&C[row * (long)ldc + col], v);
                } else {
                    C[row * (long)ldc + col] = v;
                }
            }
        }
    }
}

// ---------------------------------------------------------------------------
// depthwise causal conv(4) + bias + SiLU; writes xi as bf16 hi/lo split.
// ---------------------------------------------------------------------------
__global__ __launch_bounds__(256)
void conv_silu_split(const float* __restrict__ xi_pre, const float* __restrict__ cw,
                     const float* __restrict__ cb, u16* __restrict__ xih,
                     u16* __restrict__ xil)
{
    int t = blockIdx.x * 256 + threadIdx.x;      // B*L*512
    int d4 = (t & 511) * 4;
    int l  = (t >> 9) & (Lq - 1);
    int b  = t >> 20;
    const float* base = xi_pre + ((size_t)b * Lq) * DI + d4;
    floatx4 w0 = *(const floatx4*)(cw + (size_t)(d4 + 0) * 4);
    floatx4 w1 = *(const floatx4*)(cw + (size_t)(d4 + 1) * 4);
    floatx4 w2 = *(const floatx4*)(cw + (size_t)(d4 + 2) * 4);
    floatx4 w3 = *(const floatx4*)(cw + (size_t)(d4 + 3) * 4);
    floatx4 o  = *(const floatx4*)(cb + d4);
#pragma unroll
    for (int j = 0; j < 4; j++) {
        int ls = l - 3 + j;
        if (ls < 0) continue;
        floatx4 xv = *(const floatx4*)(base + (size_t)ls * DI);
        o[0] = fmaf(w0[j], xv[0], o[0]);
        o[1] = fmaf(w1[j], xv[1], o[1]);
        o[2] = fmaf(w2[j], xv[2], o[2]);
        o[3] = fmaf(w3[j], xv[3], o[3]);
    }
    size_t oidx = ((size_t)b * Lq + l) * DI + d4;
    ushortx4 h, lo;
#pragma unroll
    for (int i = 0; i < 4; i++) {
        float v = silu_f(o[i]);
        h[i]  = f2b(v);
        lo[i] = f2b(v - b2f(h[i]));
    }
    *(ushortx4*)(xih + oidx) = h;
    *(ushortx4*)(xil + oidx) = lo;
}

// ---------------------------------------------------------------------------
// selective scan, 3-phase chunked. n-states split across lane pairs:
// thread handles 8 of the 16 states; partner lane (t^1) has the other 8.
// ---------------------------------------------------------------------------
__global__ __launch_bounds__(256)
void scanA2(const u16* __restrict__ xih, const u16* __restrict__ xil,
            const float* __restrict__ dt, const float* __restrict__ xdbl,
            const float* __restrict__ A_log, float* __restrict__ P, float* __restrict__ S)
{
    int t  = blockIdx.x * 256 + threadIdx.x;     // B*NC*DI*2 = 131072
    int nh = t & 1;
    int d  = (t >> 1) & (DI - 1);
    int c  = (t >> 12) & (NC - 1);
    int b  = t >> 16;
    int n0 = nh * 8;

    float Aar[8];
    const floatx4* ap = (const floatx4*)(A_log + (size_t)d * NST + n0);
#pragma unroll
    for (int q = 0; q < 2; q++) {
        floatx4 av = ap[q];
#pragma unroll
        for (int i = 0; i < 4; i++) Aar[q * 4 + i] = -__expf(av[i]);
    }
    float h[8], Pr[8];
#pragma unroll
    for (int n = 0; n < 8; n++) { h[n] = 0.f; Pr[n] = 1.f; }

    int l0 = c * CL;
    size_t xbase = ((size_t)b * Lq + l0) * DI + d;
    size_t rbase = ((size_t)b * Lq + l0) * 96 + DTR + n0;
    for (int l = 0; l < CL; l++) {
        size_t xi_ = xbase + (size_t)l * DI;
        float dtv = dt[xi_];
        float xiv = b2f(xih[xi_]) + b2f(xil[xi_]);
        float dx  = dtv * xiv;
        const floatx4* bp = (const floatx4*)(xdbl + rbase + (size_t)l * 96);
        float Bv[8];
#pragma unroll
        for (int q = 0; q < 2; q++) {
            floatx4 v = bp[q];
#pragma unroll
            for (int i = 0; i < 4; i++) Bv[q * 4 + i] = v[i];
        }
#pragma unroll
        for (int n = 0; n < 8; n++) {
            float dA = __expf(dtv * Aar[n]);
            h[n] = fmaf(dA, h[n], dx * Bv[n]);
            Pr[n] *= dA;
        }
    }
    size_t obase = ((size_t)(b * NC + c) * NST + n0) * DI + d;
#pragma unroll
    for (int n = 0; n < 8; n++) {
        P[obase + (size_t)n * DI] = Pr[n];
        S[obase + (size_t)n * DI] = h[n];
    }
}

// NOTE: S and Hin may alias (element-wise read-before-write) — no __restrict__.
__global__ __launch_bounds__(256)
void scanB(const float* P, const float* S, float* Hin)
{
    int t = blockIdx.x * 256 + threadIdx.x;
    if (t >= Bq * DI) return;
    int d = t & (DI - 1);
    int b = t >> 11;
    float H[NST];
#pragma unroll
    for (int n = 0; n < NST; n++) H[n] = 0.f;
    for (int c = 0; c < NC; c++) {
        size_t base = ((size_t)(b * NC + c) * NST) * DI + d;
#pragma unroll
        for (int n = 0; n < NST; n++) {
            size_t idx = base + (size_t)n * DI;
            float p = P[idx];
            float s = S[idx];
            Hin[idx] = H[n];
            H[n] = fmaf(p, H[n], s);
        }
    }
}

// reads xi-split at [idx], writes gated-split at [idx] (lane nh==0 writes).
__global__ __launch_bounds__(256)
void scanC2(u16* xgh, u16* xgl,
            const float* __restrict__ dt, const float* __restrict__ xdbl,
            const float* __restrict__ A_log, const float* __restrict__ Dsk,
            const float* __restrict__ Hin, const float* __restrict__ z)
{
    int t  = blockIdx.x * 256 + threadIdx.x;     // 131072
    int nh = t & 1;
    int d  = (t >> 1) & (DI - 1);
    int c  = (t >> 12) & (NC - 1);
    int b  = t >> 16;
    int n0 = nh * 8;

    float Aar[8];
    const floatx4* ap = (const floatx4*)(A_log + (size_t)d * NST + n0);
#pragma unroll
    for (int q = 0; q < 2; q++) {
        floatx4 av = ap[q];
#pragma unroll
        for (int i = 0; i < 4; i++) Aar[q * 4 + i] = -__expf(av[i]);
    }
    float h[8];
    size_t hbase = ((size_t)(b * NC + c) * NST + n0) * DI + d;
#pragma unroll
    for (int n = 0; n < 8; n++) h[n] = Hin[hbase + (size_t)n * DI];

    float Dv = Dsk[d];
    int l0 = c * CL;
    size_t xbase = ((size_t)b * Lq + l0) * DI + d;
    size_t rbase = ((size_t)b * Lq + l0) * 96 + DTR + n0;
    for (int l = 0; l < CL; l++) {
        size_t xi_ = xbase + (size_t)l * DI;
        float dtv = dt[xi_];
        float xiv = b2f(xgh[xi_]) + b2f(xgl[xi_]);
        float dx  = dtv * xiv;
        const float* row = xdbl + rbase + (size_t)l * 96;
        float Bv[8], Cv[8];
#pragma unroll
        for (int q = 0; q < 2; q++) {
            floatx4 v = *(const floatx4*)(row + q * 4);
            floatx4 w = *(const floatx4*)(row + NST + q * 4);   // C block is +16 cols
#pragma unroll
            for (int i = 0; i < 4; i++) { Bv[q * 4 + i] = v[i]; Cv[q * 4 + i] = w[i]; }
        }
        float y = 0.f;
#pragma unroll
        for (int n = 0; n < 8; n++) {
            float dA = __expf(dtv * Aar[n]);
            h[n] = fmaf(dA, h[n], dx * Bv[n]);
            y = fmaf(h[n], Cv[n], y);
        }
        y += __shfl_xor(y, 1);                   // combine both 8-state halves
        y = fmaf(Dv, xiv, y);
        float zv = z[xi_];
        float g = y * silu_f(zv);
        if (nh == 0) {
            u16 gh = f2b(g);
            xgh[xi_] = gh;
            xgl[xi_] = f2b(g - b2f(gh));
        }
    }
}

// ---------------------------------------------------------------------------
extern "C" void kernel_launch(void* const* d_in, const int* in_sizes, int n_in,
                              void* d_out, int out_size, void* d_ws, size_t ws_size,
                              hipStream_t stream)
{
    const float* x      = (const float*)d_in[0];
    const float* W_in   = (const float*)d_in[1];
    const float* conv_w = (const float*)d_in[2];
    const float* conv_b = (const float*)d_in[3];
    const float* W_x    = (const float*)d_in[4];
    const float* W_dt   = (const float*)d_in[5];
    const float* b_dt   = (const float*)d_in[6];
    const float* W_out  = (const float*)d_in[7];
    const float* A_log  = (const float*)d_in[8];
    const float* D_skip = (const float*)d_in[9];
    float* out = (float*)d_out;

    float* ws     = (float*)d_ws;
    float* xi_pre = ws + W_XIPRE;        // later reused as dt
    float* dt     = xi_pre;
    float* z      = ws + W_Z;
    float* xdbl   = ws + W_XDBL;
    float* Pb     = ws + W_PB;
    float* Sb     = ws + W_SB;           // also Hin (aliased in scanB)
    u16* r1  = (u16*)(ws + W_R1);
    u16* xhi = r1, *xlo = r1 + 4194304, *winh = r1 + 8388608, *winl = r1 + 12582912;
    u16* xih = r1, *xil = r1 + 8388608;  // phase2: xi split; phase3: gated split
    u16* smal = (u16*)(ws + W_SM);
    u16* dth = smal + U_DTH,  *dtl = smal + U_DTL;
    u16* wdth = smal + U_WDTH, *wdtl = smal + U_WDTL;
    u16* wxh = smal + U_WXH,  *wxl = smal + U_WXL;
    // W_out split: hi fills Pb (dead after scanB), lo fills Sb (dead after scanC).
    u16* wouth = (u16*)Pb, *woutl = (u16*)Sb;

    // 1) split x + W_in (fused)
    split_bf16_x2<<<8192, 256, 0, stream>>>(x, xhi, xlo, 1048576,
                                            W_in, winh, winl, 1048576);
    // 2) xz = x @ W_in.T  -> xi_pre | z   (M=4096, N=4096, K=1024)
    gemm_split<2, 2, 4, 4, 2><<<dim3(32, 32), 256, 0, stream>>>(
        xhi, xlo, winh, winl, xi_pre, z, nullptr, MR, 4096, Dq, Dq, Dq, 2048, 2048);
    // 3) conv + silu -> xi split (overwrites phase1 splits; GEMM1 consumed them)
    conv_silu_split<<<8192, 256, 0, stream>>>(xi_pre, conv_w, conv_b, xih, xil);
    // 4) split W_x + W_dt (fused), zero xdbl (graph-replay safe), then
    //    x_dbl = xi @ W_x.T (M=4096, N=96, K=2048) split-K=4 with atomicAdd
    split_bf16_x2<<<320, 256, 0, stream>>>(W_x, wxh, wxl, 49152,
                                           W_dt, wdth, wdtl, 32768);
    zero_f32<<<384, 256, 0, stream>>>(xdbl, 98304);
    gemm_split<2, 2, 2, 1, 3><<<dim3(3, 64, 4), 256, 0, stream>>>(
        xih, xil, wxh, wxl, xdbl, nullptr, nullptr, MR, 96, DI, DI, DI, 96, 0);
    // 5) dt = softplus(x_dbl[:, :64] @ W_dt.T + b_dt)  (M=4096, N=2048, K=64)
    split_dtin<<<256, 256, 0, stream>>>(xdbl, dth, dtl);
    gemm_split<2, 2, 4, 4, 1><<<dim3(16, 32), 256, 0, stream>>>(
        dth, dtl, wdth, wdtl, dt, nullptr, b_dt, MR, DI, DTR, DTR, DTR, DI, 0);
    // 6) selective scan (3-phase, lane-pair n-split) + gating
    scanA2<<<512, 256, 0, stream>>>(xih, xil, dt, xdbl, A_log, Pb, Sb);
    scanB<<<16, 256, 0, stream>>>(Pb, Sb, Sb);
    scanC2<<<512, 256, 0, stream>>>(xih, xil, dt, xdbl, A_log, D_skip, Sb, z);
    // 7) split W_out AFTER scanC (Pb and Sb both dead now), then final GEMM
    //    (M=4096, N=1024, K=2048) with BM=128/BN=64 -> 512 blocks (2/CU)
    split_bf16<<<2048, 256, 0, stream>>>(W_out, wouth, woutl, 524288);
    gemm_split<2, 2, 4, 2, 0><<<dim3(16, 32), 256, 0, stream>>>(
        xih, xil, wouth, woutl, out, nullptr, nullptr, MR, Dq, DI, DI, DI, Dq, 0);
}

// Round 5
// 378.759 us; speedup vs baseline: 4.2732x; 1.4121x over previous
//
#include <hip/hip_runtime.h>
#include <math.h>

typedef float          floatx4  __attribute__((ext_vector_type(4)));
typedef unsigned int   uintx4   __attribute__((ext_vector_type(4)));
typedef unsigned short ushortx4 __attribute__((ext_vector_type(4)));
typedef unsigned short u16;

constexpr int Bq  = 2;
constexpr int Lq  = 2048;
constexpr int Dq  = 1024;
constexpr int DI  = 2048;
constexpr int DTR = 64;
constexpr int NST = 16;
constexpr int MR  = Bq * Lq;          // 4096
constexpr int NC  = 16;               // scan chunks
constexpr int CL  = Lq / NC;          // 128

// ---------------- workspace layout (f32 words) — same footprint as r4 (~113MB) ---
constexpr size_t NWB     = (size_t)MR * DI;          // 8,388,608
constexpr size_t W_XIPRE = 0;                        // xi_pre f32; later dt f32
constexpr size_t W_Z     = NWB;                      // z f32
constexpr size_t W_XDBL  = 2 * NWB;                  // MR x 96 f32
constexpr size_t SZ_XDBL = (size_t)MR * 96;
constexpr size_t SZ_PS   = (size_t)Bq * NC * NST * DI;   // 1,048,576 f32
constexpr size_t W_PB    = W_XDBL + SZ_XDBL;         // P; later wouth (2M u16 = 1M f32, fits)
constexpr size_t W_SB    = W_PB + SZ_PS;             // S / Hin (in-place)
constexpr size_t W_R1    = W_SB + SZ_PS;             // 8.4M f32 = 16.8M u16 activations
constexpr size_t W_SM    = W_R1 + NWB;               // small splits
// u16 offsets inside R1: phase1: xhi 0, xlo 4194304, winh 8388608 (4.2M u16)
//                        phase2+: xih 0, xil 8388608
// u16 offsets inside SM:
constexpr size_t U_DTH = 0, U_DTL = 262144, U_WDT = 524288, U_WX = 655360;
// SM end = 851968 u16 -> total ws ~112.3 MB  (<= proven 114.8 MB)

__device__ __forceinline__ u16 f2b(float x) {            // f32 -> bf16 RNE
    unsigned int u = __float_as_uint(x);
    u += 0x7fffu + ((u >> 16) & 1u);
    return (u16)(u >> 16);
}
__device__ __forceinline__ float b2f(u16 h) { return __uint_as_float(((unsigned int)h) << 16); }
__device__ __forceinline__ float silu_f(float x) { return x / (1.f + __expf(-x)); }

__device__ __forceinline__ void mfma16(floatx4& d, uintx4 a, uintx4 b) {
    asm("v_mfma_f32_16x16x32_bf16 %0, %1, %2, %0" : "+v"(d) : "v"(a), "v"(b));
}
__device__ __forceinline__ void gload16(const void* g, void* l) {
    __builtin_amdgcn_global_load_lds((const __attribute__((address_space(1))) void*)g,
                                     (__attribute__((address_space(3))) void*)l, 16, 0, 0);
}

// ---------------------------------------------------------------------------
// helpers: split (hi+lo) and round (hi only)
// ---------------------------------------------------------------------------
__device__ __forceinline__ void split_store(const floatx4 v, u16* hi, u16* lo, size_t t) {
    ushortx4 h, l;
#pragma unroll
    for (int i = 0; i < 4; i++) {
        h[i] = f2b(v[i]);
        l[i] = f2b(v[i] - b2f(h[i]));
    }
    ((ushortx4*)hi)[t] = h;
    ((ushortx4*)lo)[t] = l;
}
__device__ __forceinline__ void round_store(const floatx4 v, u16* hi, size_t t) {
    ushortx4 h;
#pragma unroll
    for (int i = 0; i < 4; i++) h[i] = f2b(v[i]);
    ((ushortx4*)hi)[t] = h;
}

// one fused prep kernel: split x; round W_in, W_dt, W_x; zero xdbl
__global__ __launch_bounds__(256)
void prep(const float* __restrict__ x, u16* __restrict__ xhi, u16* __restrict__ xlo,
          const float* __restrict__ W_in, u16* __restrict__ winh,
          const float* __restrict__ W_x, u16* __restrict__ wxh,
          const float* __restrict__ W_dt, u16* __restrict__ wdth,
          float* __restrict__ xdbl)
{
    int t = blockIdx.x * 256 + threadIdx.x;
    if (t < 1048576) { split_store(((const floatx4*)x)[t], xhi, xlo, t); return; }
    t -= 1048576;
    if (t < 1048576) { round_store(((const floatx4*)W_in)[t], winh, t); return; }
    t -= 1048576;
    if (t < 49152)   { round_store(((const floatx4*)W_x)[t], wxh, t); return; }
    t -= 49152;
    if (t < 32768)   { round_store(((const floatx4*)W_dt)[t], wdth, t); return; }
    t -= 32768;
    if (t < 98304)   ((floatx4*)xdbl)[t] = (floatx4){0.f, 0.f, 0.f, 0.f};
}

__global__ __launch_bounds__(256)
void round_bf16(const float* __restrict__ src, u16* __restrict__ hi, int n4)
{
    int t = blockIdx.x * 256 + threadIdx.x;
    if (t < n4) round_store(((const floatx4*)src)[t], hi, t);
}

// extract + split cols 0..63 of xdbl (ld 96) into dense (ld 64) hi/lo
__global__ __launch_bounds__(256)
void split_dtin(const float* __restrict__ xdbl, u16* __restrict__ hi, u16* __restrict__ lo)
{
    int t = blockIdx.x * 256 + threadIdx.x;      // MR*16
    if (t >= MR * 16) return;
    int r = t >> 4, c4 = (t & 15) * 4;
    floatx4 v = *(const floatx4*)(xdbl + (size_t)r * 96 + c4);
    ushortx4 h, l;
#pragma unroll
    for (int i = 0; i < 4; i++) { h[i] = f2b(v[i]); l[i] = f2b(v[i] - b2f(h[i])); }
    *(ushortx4*)(hi + (size_t)r * 64 + c4) = h;
    *(ushortx4*)(lo + (size_t)r * 64 + c4) = l;
}

// ---------------------------------------------------------------------------
// 2-term split MFMA GEMM: C = (Ah+Al) . Bh^T, K-major both sides.
// BK=64, XOR-swizzled LDS (chunk kc ^= row&7, applied on global src AND ds_read).
// EPI: 0 plain f32, 1 bias+softplus f32, 2 split-dest f32/f32, 3 atomicAdd f32
// ---------------------------------------------------------------------------
__device__ __forceinline__ void stage64(const u16* g, u16* s, int rows, int ld,
                                        int k0, int wave, int lane)
{
    const int chunks = rows * 8;                 // 16B chunks per tile (row = 64 u16)
    for (int c0 = wave * 64; c0 < chunks; c0 += 256) {
        int c   = c0 + lane;
        int row = c >> 3;
        int kcg = (c & 7) ^ (row & 7);           // inverse-swizzled global source
        const u16* gp = g + (size_t)row * ld + k0 + kcg * 8;
        gload16(gp, s + (size_t)c0 * 8);         // wave-uniform base; HW adds lane*16B
    }
}

template <int WM, int WN, int FM, int FN, int EPI>
__global__ __launch_bounds__(256)
void gemm2t(const u16* __restrict__ Ah, const u16* __restrict__ Al,
            const u16* __restrict__ Bh,
            float* __restrict__ C, float* __restrict__ C2,
            const float* __restrict__ bias,
            int M, int N, int K, int lda, int ldb, int ldc, int nsplit)
{
    constexpr int BM = WM * FM * 16, BN = WN * FN * 16, BK = 64;
    __shared__ u16 sm[(2 * BM + BN) * BK];
    u16* sAh = sm;
    u16* sAl = sm + BM * BK;
    u16* sBh = sm + 2 * BM * BK;

    const int tid = threadIdx.x, lane = tid & 63, wave = tid >> 6;
    const int wm = wave % WM, wn = wave / WM;
    const long m0 = (long)blockIdx.y * BM, n0 = (long)blockIdx.x * BN;
    const int frr = lane & 15;

    const int kchunk = K / gridDim.z;
    const int kBeg = blockIdx.z * kchunk;
    const int kEnd = kBeg + kchunk;

    floatx4 acc[FM][FN];
#pragma unroll
    for (int i = 0; i < FM; i++)
#pragma unroll
        for (int j = 0; j < FN; j++) acc[i][j] = (floatx4){0.f, 0.f, 0.f, 0.f};

    const u16* gAh = Ah + (size_t)m0 * lda;
    const u16* gAl = Al + (size_t)m0 * lda;
    const u16* gBh = Bh + (size_t)n0 * ldb;

    for (int k0 = kBeg; k0 < kEnd; k0 += BK) {
        stage64(gAh, sAh, BM, lda, k0, wave, lane);
        stage64(gAl, sAl, BM, lda, k0, wave, lane);
        stage64(gBh, sBh, BN, ldb, k0, wave, lane);
        __syncthreads();                          // drains vmcnt for gload_lds

#pragma unroll
        for (int kk = 0; kk < 2; kk++) {
            const int kc = kk * 4 + (lane >> 4);  // 16B chunk within row (pre-swizzle)
            uintx4 af[FM], bb[FN];
#pragma unroll
            for (int f = 0; f < FN; f++) {
                int r = (wn * FN + f) * 16 + frr;
                bb[f] = *(const uintx4*)(sBh + r * 64 + (kc ^ (r & 7)) * 8);
            }
#pragma unroll
            for (int f = 0; f < FM; f++) {
                int r = (wm * FM + f) * 16 + frr;
                af[f] = *(const uintx4*)(sAh + r * 64 + (kc ^ (r & 7)) * 8);
            }
#pragma unroll
            for (int fm = 0; fm < FM; fm++)
#pragma unroll
                for (int fn = 0; fn < FN; fn++)
                    mfma16(acc[fm][fn], af[fm], bb[fn]);
#pragma unroll
            for (int f = 0; f < FM; f++) {
                int r = (wm * FM + f) * 16 + frr;
                af[f] = *(const uintx4*)(sAl + r * 64 + (kc ^ (r & 7)) * 8);
            }
#pragma unroll
            for (int fm = 0; fm < FM; fm++)
#pragma unroll
                for (int fn = 0; fn < FN; fn++)
                    mfma16(acc[fm][fn], af[fm], bb[fn]);
        }
        __syncthreads();
    }

#pragma unroll
    for (int fm = 0; fm < FM; fm++) {
        long row0 = m0 + (wm * FM + fm) * 16 + ((lane >> 4) << 2);
#pragma unroll
        for (int fn = 0; fn < FN; fn++) {
            long col = n0 + (wn * FN + fn) * 16 + (lane & 15);
#pragma unroll
            for (int i = 0; i < 4; i++) {
                long row = row0 + i;
                float v = acc[fm][fn][i];
                if constexpr (EPI == 1) {
                    v += bias[col];
                    v = (v > 20.f) ? v : log1pf(__expf(v));
                    C[row * (long)ldc + col] = v;
                } else if constexpr (EPI == 2) {
                    if (col < nsplit) C[row * (long)nsplit + col] = v;
                    else              C2[row * (long)nsplit + (col - nsplit)] = v;
                } else if constexpr (EPI == 3) {
                    atomicAdd(&C[row * (long)ldc + col], v);
                } else {
                    C[row * (long)ldc + col] = v;
                }
            }
        }
    }
}

// ---------------------------------------------------------------------------
// depthwise causal conv(4) + bias + SiLU; writes xi as bf16 hi/lo split.
// ---------------------------------------------------------------------------
__global__ __launch_bounds__(256)
void conv_silu_split(const float* __restrict__ xi_pre, const float* __restrict__ cw,
                     const float* __restrict__ cb, u16* __restrict__ xih,
                     u16* __restrict__ xil)
{
    int t = blockIdx.x * 256 + threadIdx.x;      // B*L*512
    int d4 = (t & 511) * 4;
    int l  = (t >> 9) & (Lq - 1);
    int b  = t >> 20;
    const float* base = xi_pre + ((size_t)b * Lq) * DI + d4;
    floatx4 w0 = *(const floatx4*)(cw + (size_t)(d4 + 0) * 4);
    floatx4 w1 = *(const floatx4*)(cw + (size_t)(d4 + 1) * 4);
    floatx4 w2 = *(const floatx4*)(cw + (size_t)(d4 + 2) * 4);
    floatx4 w3 = *(const floatx4*)(cw + (size_t)(d4 + 3) * 4);
    floatx4 o  = *(const floatx4*)(cb + d4);
#pragma unroll
    for (int j = 0; j < 4; j++) {
        int ls = l - 3 + j;
        if (ls < 0) continue;
        floatx4 xv = *(const floatx4*)(base + (size_t)ls * DI);
        o[0] = fmaf(w0[j], xv[0], o[0]);
        o[1] = fmaf(w1[j], xv[1], o[1]);
        o[2] = fmaf(w2[j], xv[2], o[2]);
        o[3] = fmaf(w3[j], xv[3], o[3]);
    }
    size_t oidx = ((size_t)b * Lq + l) * DI + d4;
    ushortx4 h, lo;
#pragma unroll
    for (int i = 0; i < 4; i++) {
        float v = silu_f(o[i]);
        h[i]  = f2b(v);
        lo[i] = f2b(v - b2f(h[i]));
    }
    *(ushortx4*)(xih + oidx) = h;
    *(ushortx4*)(xil + oidx) = lo;
}

// ---------------------------------------------------------------------------
// selective scan, 3-phase. 4 states per thread (4-lane groups share (b,c,d)).
// threads = B*NC*DI*4 = 262144 -> 4 waves/SIMD.
// ---------------------------------------------------------------------------
__global__ __launch_bounds__(256)
void scanA4(const u16* __restrict__ xih, const u16* __restrict__ xil,
            const float* __restrict__ dt, const float* __restrict__ xdbl,
            const float* __restrict__ A_log, float* __restrict__ P, float* __restrict__ S)
{
    int t  = blockIdx.x * 256 + threadIdx.x;
    int nh = t & 3;
    int d  = (t >> 2) & (DI - 1);
    int c  = (t >> 13) & (NC - 1);
    int b  = t >> 17;
    int n0 = nh * 4;

    floatx4 av = *(const floatx4*)(A_log + (size_t)d * NST + n0);
    float Aar[4];
#pragma unroll
    for (int i = 0; i < 4; i++) Aar[i] = -__expf(av[i]);

    float h[4], Pr[4];
#pragma unroll
    for (int n = 0; n < 4; n++) { h[n] = 0.f; Pr[n] = 1.f; }

    int l0 = c * CL;
    size_t xbase = ((size_t)b * Lq + l0) * DI + d;
    size_t rbase = ((size_t)b * Lq + l0) * 96 + DTR + n0;
    for (int l = 0; l < CL; l++) {
        size_t xi_ = xbase + (size_t)l * DI;
        float dtv = dt[xi_];
        float xiv = b2f(xih[xi_]) + b2f(xil[xi_]);
        float dx  = dtv * xiv;
        floatx4 bv = *(const floatx4*)(xdbl + rbase + (size_t)l * 96);
#pragma unroll
        for (int n = 0; n < 4; n++) {
            float dA = __expf(dtv * Aar[n]);
            h[n] = fmaf(dA, h[n], dx * bv[n]);
            Pr[n] *= dA;
        }
    }
    size_t obase = ((size_t)(b * NC + c) * NST + n0) * DI + d;
#pragma unroll
    for (int n = 0; n < 4; n++) {
        P[obase + (size_t)n * DI] = Pr[n];
        S[obase + (size_t)n * DI] = h[n];
    }
}

// one thread per (b,n,d); serial over chunks. S and Hin alias (same-thread RW).
__global__ __launch_bounds__(256)
void scanB2(const float* P, const float* S, float* Hin)
{
    int t = blockIdx.x * 256 + threadIdx.x;      // B*NST*DI = 65536
    int d = t & (DI - 1);
    int n = (t >> 11) & (NST - 1);
    int b = t >> 15;
    float H = 0.f;
    for (int c = 0; c < NC; c++) {
        size_t idx = (((size_t)(b * NC + c) * NST) + n) * DI + d;
        float p = P[idx];
        float s = S[idx];
        Hin[idx] = H;
        H = fmaf(p, H, s);
    }
}

// replay + y-reduce over 4-lane group + gating; writes gated split (lane nh==0).
__global__ __launch_bounds__(256)
void scanC4(u16* xgh, u16* xgl,
            const float* __restrict__ dt, const float* __restrict__ xdbl,
            const float* __restrict__ A_log, const float* __restrict__ Dsk,
            const float* __restrict__ Hin, const float* __restrict__ z)
{
    int t  = blockIdx.x * 256 + threadIdx.x;
    int nh = t & 3;
    int d  = (t >> 2) & (DI - 1);
    int c  = (t >> 13) & (NC - 1);
    int b  = t >> 17;
    int n0 = nh * 4;

    floatx4 av = *(const floatx4*)(A_log + (size_t)d * NST + n0);
    float Aar[4];
#pragma unroll
    for (int i = 0; i < 4; i++) Aar[i] = -__expf(av[i]);

    float h[4];
    size_t hbase = ((size_t)(b * NC + c) * NST + n0) * DI + d;
#pragma unroll
    for (int n = 0; n < 4; n++) h[n] = Hin[hbase + (size_t)n * DI];

    float Dv = Dsk[d];
    int l0 = c * CL;
    size_t xbase = ((size_t)b * Lq + l0) * DI + d;
    size_t rbase = ((size_t)b * Lq + l0) * 96 + DTR + n0;
    for (int l = 0; l < CL; l++) {
        size_t xi_ = xbase + (size_t)l * DI;
        float dtv = dt[xi_];
        float xiv = b2f(xgh[xi_]) + b2f(xgl[xi_]);
        float dx  = dtv * xiv;
        const float* row = xdbl + rbase + (size_t)l * 96;
        floatx4 bv = *(const floatx4*)(row);
        floatx4 cv = *(const floatx4*)(row + NST);      // C block is +16 cols
        float y = 0.f;
#pragma unroll
        for (int n = 0; n < 4; n++) {
            float dA = __expf(dtv * Aar[n]);
            h[n] = fmaf(dA, h[n], dx * bv[n]);
            y = fmaf(h[n], cv[n], y);
        }
        y += __shfl_xor(y, 1);
        y += __shfl_xor(y, 2);                  // full 16-state sum in all 4 lanes
        y = fmaf(Dv, xiv, y);
        float g = y * silu_f(z[xi_]);
        if (nh == 0) {
            u16 gh = f2b(g);
            xgh[xi_] = gh;
            xgl[xi_] = f2b(g - b2f(gh));
        }
    }
}

// ---------------------------------------------------------------------------
extern "C" void kernel_launch(void* const* d_in, const int* in_sizes, int n_in,
                              void* d_out, int out_size, void* d_ws, size_t ws_size,
                              hipStream_t stream)
{
    const float* x      = (const float*)d_in[0];
    const float* W_in   = (const float*)d_in[1];
    const float* conv_w = (const float*)d_in[2];
    const float* conv_b = (const float*)d_in[3];
    const float* W_x    = (const float*)d_in[4];
    const float* W_dt   = (const float*)d_in[5];
    const float* b_dt   = (const float*)d_in[6];
    const float* W_out  = (const float*)d_in[7];
    const float* A_log  = (const float*)d_in[8];
    const float* D_skip = (const float*)d_in[9];
    float* out = (float*)d_out;

    float* ws     = (float*)d_ws;
    float* xi_pre = ws + W_XIPRE;        // later reused as dt (f32)
    float* dt     = xi_pre;
    float* z      = ws + W_Z;
    float* xdbl   = ws + W_XDBL;
    float* Pb     = ws + W_PB;
    float* Sb     = ws + W_SB;           // also Hin (in-place in scanB2)
    u16* r1   = (u16*)(ws + W_R1);
    u16* xhi  = r1, *xlo = r1 + 4194304, *winh = r1 + 8388608;
    u16* xih  = r1, *xil = r1 + 8388608;    // phase2: xi split; phase3: gated split
    u16* smal = (u16*)(ws + W_SM);
    u16* dth  = smal + U_DTH, *dtl = smal + U_DTL;
    u16* wdth = smal + U_WDT, *wxh = smal + U_WX;
    u16* wouth = (u16*)Pb;               // P region reused AFTER scanB2 (P dead)

    // 1) prep: split x; round W_in/W_x/W_dt; zero xdbl
    prep<<<8896, 256, 0, stream>>>(x, xhi, xlo, W_in, winh, W_x, wxh, W_dt, wdth, xdbl);
    // 2) xz = x @ W_in.T -> xi_pre | z  (M=4096, N=4096, K=1024)
    gemm2t<2, 2, 4, 4, 2><<<dim3(32, 32), 256, 0, stream>>>(
        xhi, xlo, winh, xi_pre, z, nullptr, MR, 4096, Dq, Dq, Dq, 2048, 2048);
    // 3) conv + silu -> xi split (overwrites xhi/xlo/winh; GEMM1 consumed them)
    conv_silu_split<<<8192, 256, 0, stream>>>(xi_pre, conv_w, conv_b, xih, xil);
    // 4) x_dbl = xi @ W_x.T (M=4096, N=96, K=2048), split-K=4 atomic
    gemm2t<2, 2, 2, 1, 3><<<dim3(3, 64, 4), 256, 0, stream>>>(
        xih, xil, wxh, xdbl, nullptr, nullptr, MR, 96, DI, DI, DI, 96, 0);
    // 5) dt = softplus(x_dbl[:, :64] @ W_dt.T + b_dt) (M=4096, N=2048, K=64)
    split_dtin<<<256, 256, 0, stream>>>(xdbl, dth, dtl);
    gemm2t<2, 2, 4, 4, 1><<<dim3(16, 32), 256, 0, stream>>>(
        dth, dtl, wdth, dt, nullptr, b_dt, MR, DI, DTR, DTR, DTR, DI, 0);
    // 6) selective scan (3-phase, 4-lane-group n-split) + gating
    scanA4<<<1024, 256, 0, stream>>>(xih, xil, dt, xdbl, A_log, Pb, Sb);
    scanB2<<<256, 256, 0, stream>>>(Pb, Sb, Sb);
    round_bf16<<<2048, 256, 0, stream>>>(W_out, wouth, 524288);   // P dead now
    scanC4<<<1024, 256, 0, stream>>>(xih, xil, dt, xdbl, A_log, D_skip, Sb, z);
    // 7) out = gated @ W_out.T (M=4096, N=1024, K=2048), BM=128/BN=64
    gemm2t<2, 2, 4, 2, 0><<<dim3(16, 32), 256, 0, stream>>>(
        xih, xil, wouth, out, nullptr, nullptr, MR, Dq, DI, DI, DI, Dq, 0);
}